// Round 5
// baseline (12855.986 us; speedup 1.0000x reference)
//
#include <hip/hip_runtime.h>

// Farthest Point Sampling: points (B, N, 3) fp32 -> indices (B, M) int32.
// B=16, N=65536, M=2048.  Reference semantics (locked, absmax=0):
// float64 pipeline: dx=(double)x-(double)cx; d=((dx*dx+dy*dy)+dz*dz) with
// separate rounding (no FMA); min via fmin; argmax first-index tie-break.
//
// Round 10: per-wave publish, ZERO in-loop barriers.
// R3/R4 verdict: agent (MALL) transport already completes in ~1 poll round
// (FETCH 135 KB/iter == one round); CAS/L2-local polling serializes on L2
// banks and is net slower.  The remaining cost is the per-iteration SERIAL
// section: barrier -> wave0-only (LDS reduce + publish + poll + reduce +
// LDS broadcast) -> barrier, with waves 1-7 idle throughout.
// New structure per iteration (per batch: 16 blocks x 8 waves = 128 waves):
//   * every wave butterflies its own 512 points and publishes its WAVE
//     partial (v, idx, coords) to its own 32-B slot immediately — no
//     intra-block reduce, no barrier.
//   * wave0 of each block polls all 128 slots (64 lanes x 2 slots),
//     reduces 128-way (lexmax, min-idx tie-break), writes the centroid to
//     a tagged LDS mailbox; waves 1-7 spin on the mailbox (intra-CU LDS,
//     ~50 cy) instead of a barrier.
//   * slot packing, tags, parity reuse, poison, and all f64 math are
//     byte-identical to the proven baseline.
// Deadlock/overwrite safety (induction at wave granularity): reader X's
// read of slot(w,m) precedes X's publish(m+1) [program order]; X's
// publish(m+1) gates every wave0's poll(m+1); that gates w's receipt of
// c_{m+1} (fabric or LDS mailbox); which precedes w's overwrite at m+2.
// Tags catch any tear; parity separates m from m+1.
//
// ws need: 2 parities x 16 batches x 128 slots x 32 B = 128 KB.  If the
// harness workspace is smaller, kernel_launch falls back to the verbatim
// proven baseline kernel (5839 us) — worst case is the baseline.

#define N_PTS   65536
#define M_SAMP  2048
#define NT      512
#define BPB     16                  // blocks per batch
#define PTS_BLK (N_PTS / BPB)       // 4096
#define PPT     (PTS_BLK / NT)      // 8 points per thread
#define NWAVES  (NT / 64)           // 8
#define NBATCH  16

typedef unsigned long long u64;

__device__ __forceinline__ u64 ld_agent(const u64* a) {
  return __hip_atomic_load(a, __ATOMIC_RELAXED, __HIP_MEMORY_SCOPE_AGENT);
}
__device__ __forceinline__ void st_agent(u64* a, u64 v) {
  __hip_atomic_store(a, v, __ATOMIC_RELAXED, __HIP_MEMORY_SCOPE_AGENT);
}
__device__ __forceinline__ u64 ld_lds(const u64* a) {
  return __hip_atomic_load(a, __ATOMIC_RELAXED, __HIP_MEMORY_SCOPE_WORKGROUP);
}
__device__ __forceinline__ void st_lds(u64* a, u64 v) {
  __hip_atomic_store(a, v, __ATOMIC_RELAXED, __HIP_MEMORY_SCOPE_WORKGROUP);
}

// ---------------------------------------------------------------------------
// New kernel: per-wave publish, no in-loop barriers.
// Slot layout: ws[ par ][ batch ][ rank*NWAVES + wave ] of 4 u64 (32 B):
//   A = value_lo32<<32 | m<<16 | idx          (idx<65536: 16b)
//   B = value_hi32<<32 | m<<16 | idx
//   C = x_bits<<32     | m<<16 | y_hi16
//   D = y_lo16<<48     | z_bits<<16 | m
// ---------------------------------------------------------------------------
#define WSLOT_U64 4
#define SLOTS_PER_BATCH (BPB * NWAVES)                       // 128
#define WREGION_U64 (NBATCH * SLOTS_PER_BATCH * WSLOT_U64)   // 8192 u64 / parity
#define WS_NEED ((size_t)(2 * WREGION_U64) * 8)              // 128 KB

__global__ __launch_bounds__(NT, 2)
void fps_wavepub(const float* __restrict__ pts, int* __restrict__ out,
                 u64* __restrict__ ws) {
  const int rank = blockIdx.x;                 // 0..BPB-1 within batch
  const int b    = blockIdx.y;                 // batch
  const float* __restrict__ p = pts + (size_t)b * (size_t)(N_PTS * 3);
  int* __restrict__ o = out + (size_t)b * M_SAMP;
  const int t = threadIdx.x;
  const int w = t >> 6, lane = t & 63;
  const int base = rank * PTS_BLK;

  __shared__ float s_pts[PTS_BLK * 3];         // 48 KB slice
  __shared__ u64   sL[2][3];                   // tagged centroid mailbox

  for (int i = t; i < PTS_BLK * 3; i += NT)
    s_pts[i] = p[base * 3 + i];
  if (rank == 0 && t == 0) o[0] = 0;
  if (t < 6) sL[t / 3][t % 3] = 0xAAAAAAAAAAAAAAAAull;   // poison mailbox
  __syncthreads();                             // only barrier in the kernel

  // Own points pre-converted to f64 in registers; (double)x is exact.
  double pd[PPT][3];
  double md[PPT];
#pragma unroll
  for (int j = 0; j < PPT; ++j) {
    const int l = t + j * NT;
    pd[j][0] = (double)s_pts[3 * l + 0];
    pd[j][1] = (double)s_pts[3 * l + 1];
    pd[j][2] = (double)s_pts[3 * l + 2];
    md[j] = 1e10;
  }

  // Seed centroid = point 0 of this batch (read-only, cached).
  double cx = (double)p[0], cy = (double)p[1], cz = (double)p[2];

  for (int m = 1; m < M_SAMP; ++m) {
    double bestv = -1.0;    // distances >= 0 always beat this
    int    besti = 0;

    // Indices base + t + j*NT ascend with j => strict '>' keeps the first
    // (lowest-index) maximum within a thread.
#pragma unroll
    for (int j = 0; j < PPT; ++j) {
      const double dx = __dsub_rn(pd[j][0], cx);
      const double dy = __dsub_rn(pd[j][1], cy);
      const double dz = __dsub_rn(pd[j][2], cz);
      const double d  = __dadd_rn(__dadd_rn(__dmul_rn(dx, dx),
                                            __dmul_rn(dy, dy)),
                                  __dmul_rn(dz, dz));
      const double nmd = fmin(md[j], d);
      md[j] = nmd;
      if (nmd > bestv) { bestv = nmd; besti = base + t + j * NT; }
    }

    // 64-lane butterfly argmax, min-index tie-break (all lanes converge).
#pragma unroll
    for (int off = 32; off >= 1; off >>= 1) {
      const double ov = __shfl_xor(bestv, off, 64);
      const int    oi = __shfl_xor(besti, off, 64);
      if (ov > bestv || (ov == bestv && oi < besti)) { bestv = ov; besti = oi; }
    }

    const u64 mm  = (u64)(unsigned)m;
    const int par = m & 1;
    u64* reg = ws + (size_t)par * WREGION_U64 +
               (size_t)b * (SLOTS_PER_BATCH * WSLOT_U64);

    // Publish THIS WAVE's partial immediately — no intra-block reduce.
    if (lane == 0) {
      const int l = besti - base;             // wave winner is in our slice
      const unsigned xb = __float_as_uint(s_pts[3 * l + 0]);
      const unsigned yb = __float_as_uint(s_pts[3 * l + 1]);
      const unsigned zb = __float_as_uint(s_pts[3 * l + 2]);
      const u64 vb = (u64)__double_as_longlong(bestv);
      const u64 ti = (mm << 16) | (u64)(unsigned)besti;
      u64* s = reg + (size_t)(rank * NWAVES + w) * WSLOT_U64;
      st_agent(s + 0, (vb << 32) | ti);
      st_agent(s + 1, (vb & 0xFFFFFFFF00000000ull) | ti);
      st_agent(s + 2, ((u64)xb << 32) | (mm << 16) | (u64)(yb >> 16));
      st_agent(s + 3, ((u64)(yb & 0xFFFFu) << 48) | ((u64)zb << 16) | mm);
    }

    if (w == 0) {
      // Wave 0: poll all 128 wave-slots of this batch (2 per lane).
      const u64* r0 = reg + (size_t)(2 * lane) * WSLOT_U64;
      const u64* r1 = reg + (size_t)(2 * lane + 1) * WSLOT_U64;
      u64 A0, B0, C0, D0, A1, B1, C1, D1;
      for (;;) {
        A0 = ld_agent(r0 + 0); B0 = ld_agent(r0 + 1);
        C0 = ld_agent(r0 + 2); D0 = ld_agent(r0 + 3);
        A1 = ld_agent(r1 + 0); B1 = ld_agent(r1 + 1);
        C1 = ld_agent(r1 + 2); D1 = ld_agent(r1 + 3);
        const bool ok = (((A0 >> 16) & 0xFFFFull) == mm) &
                        (((B0 >> 16) & 0xFFFFull) == mm) &
                        (((C0 >> 16) & 0xFFFFull) == mm) &
                        ((D0 & 0xFFFFull) == mm) &
                        (((A1 >> 16) & 0xFFFFull) == mm) &
                        (((B1 >> 16) & 0xFFFFull) == mm) &
                        (((C1 >> 16) & 0xFFFFull) == mm) &
                        ((D1 & 0xFFFFull) == mm);
        if (ok) break;
      }
      // Unpack both candidates.
      const double v0 = __longlong_as_double(
          (long long)((B0 & 0xFFFFFFFF00000000ull) | (A0 >> 32)));
      const double v1 = __longlong_as_double(
          (long long)((B1 & 0xFFFFFFFF00000000ull) | (A1 >> 32)));
      const int i0 = (int)(A0 & 0xFFFFull);
      const int i1 = (int)(A1 & 0xFFFFull);
      // Local merge (lexmax, min-idx tie-break).
      const bool take1 = (v1 > v0) || (v1 == v0 && i1 < i0);
      double v  = take1 ? v1 : v0;
      int    ii = take1 ? i1 : i0;
      int    src = lane | ((take1 ? 1 : 0) << 6);   // owner lane + half bit
      // 64-lane butterfly over the 128 candidates.
#pragma unroll
      for (int off = 32; off >= 1; off >>= 1) {
        const double ov = __shfl_xor(v, off, 64);
        const int    oi = __shfl_xor(ii, off, 64);
        const int    os = __shfl_xor(src, off, 64);
        if (ov > v || (ov == v && oi < ii)) { v = ov; ii = oi; src = os; }
      }
      // Winner coords: owner lane selects its winning half, then broadcast.
      const int own  = src & 63;
      const int half = src >> 6;
      unsigned sx = half ? (unsigned)(C1 >> 32) : (unsigned)(C0 >> 32);
      unsigned sy = half ? (unsigned)(((C1 & 0xFFFFull) << 16) | (D1 >> 48))
                         : (unsigned)(((C0 & 0xFFFFull) << 16) | (D0 >> 48));
      unsigned sz = half ? (unsigned)((D1 >> 16) & 0xFFFFFFFFull)
                         : (unsigned)((D0 >> 16) & 0xFFFFFFFFull);
      const unsigned cxb = (unsigned)__shfl((int)sx, own, 64);
      const unsigned cyb = (unsigned)__shfl((int)sy, own, 64);
      const unsigned czb = (unsigned)__shfl((int)sz, own, 64);
      if (lane == 0) {
        st_lds(&sL[par][0], ((u64)cxb << 32) | mm);
        st_lds(&sL[par][1], ((u64)cyb << 32) | mm);
        st_lds(&sL[par][2], ((u64)czb << 32) | mm);
        if (rank == 0) o[m] = ii;
      }
      cx = (double)__uint_as_float(cxb);
      cy = (double)__uint_as_float(cyb);
      cz = (double)__uint_as_float(czb);
    } else {
      // Waves 1-7: spin on the tagged LDS mailbox (intra-CU, ~50 cy).
      u64 l0, l1, l2;
      for (;;) {
        l0 = ld_lds(&sL[par][0]);
        l1 = ld_lds(&sL[par][1]);
        l2 = ld_lds(&sL[par][2]);
        const bool ok = ((l0 & 0xFFFFull) == mm) &
                        ((l1 & 0xFFFFull) == mm) &
                        ((l2 & 0xFFFFull) == mm);
        if (ok) break;
      }
      cx = (double)__uint_as_float((unsigned)(l0 >> 32));
      cy = (double)__uint_as_float((unsigned)(l1 >> 32));
      cz = (double)__uint_as_float((unsigned)(l2 >> 32));
    }
  }
}

// ---------------------------------------------------------------------------
// Fallback: verbatim proven baseline (5839 us), used if ws is too small.
// ---------------------------------------------------------------------------
#define BSLOT_U64 16                // 128 B per slot

__global__ __launch_bounds__(NT, 2)
void fps_multi(const float* __restrict__ pts, int* __restrict__ out,
               u64* __restrict__ ws) {
  const int rank = blockIdx.x;
  const int b    = blockIdx.y;
  const float* __restrict__ p = pts + (size_t)b * (size_t)(N_PTS * 3);
  int* __restrict__ o = out + (size_t)b * M_SAMP;
  const int t = threadIdx.x;
  const int base = rank * PTS_BLK;

  __shared__ float  s_pts[PTS_BLK * 3];
  __shared__ double s_bv[NWAVES];
  __shared__ int    s_bi[NWAVES];
  __shared__ float  s_c[3];

  for (int i = t; i < PTS_BLK * 3; i += NT)
    s_pts[i] = p[base * 3 + i];
  if (rank == 0 && t == 0) o[0] = 0;
  if (t == 0) { s_c[0] = p[0]; s_c[1] = p[1]; s_c[2] = p[2]; }
  __syncthreads();

  double pd[PPT][3];
  double md[PPT];
#pragma unroll
  for (int j = 0; j < PPT; ++j) {
    const int l = t + j * NT;
    pd[j][0] = (double)s_pts[3 * l + 0];
    pd[j][1] = (double)s_pts[3 * l + 1];
    pd[j][2] = (double)s_pts[3 * l + 2];
    md[j] = 1e10;
  }

  for (int m = 1; m < M_SAMP; ++m) {
    const double cx = (double)s_c[0];
    const double cy = (double)s_c[1];
    const double cz = (double)s_c[2];

    double bestv = -1.0;
    int    besti = 0;
#pragma unroll
    for (int j = 0; j < PPT; ++j) {
      const double dx = __dsub_rn(pd[j][0], cx);
      const double dy = __dsub_rn(pd[j][1], cy);
      const double dz = __dsub_rn(pd[j][2], cz);
      const double d  = __dadd_rn(__dadd_rn(__dmul_rn(dx, dx),
                                            __dmul_rn(dy, dy)),
                                  __dmul_rn(dz, dz));
      const double nmd = fmin(md[j], d);
      md[j] = nmd;
      if (nmd > bestv) { bestv = nmd; besti = base + t + j * NT; }
    }
#pragma unroll
    for (int off = 32; off >= 1; off >>= 1) {
      const double ov = __shfl_xor(bestv, off, 64);
      const int    oi = __shfl_xor(besti, off, 64);
      if (ov > bestv || (ov == bestv && oi < besti)) { bestv = ov; besti = oi; }
    }
    if ((t & 63) == 0) { s_bv[t >> 6] = bestv; s_bi[t >> 6] = besti; }
    __syncthreads();

    if (t < 64) {
      if (t < NWAVES) {
        bestv = s_bv[t]; besti = s_bi[t];
#pragma unroll
        for (int off = NWAVES / 2; off >= 1; off >>= 1) {
          const double ov = __shfl_xor(bestv, off, 64);
          const int    oi = __shfl_xor(besti, off, 64);
          if (ov > bestv || (ov == bestv && oi < besti)) { bestv = ov; besti = oi; }
        }
      }
      const u64 mm  = (u64)(unsigned)m;
      const u64 grp = (u64)(((m & 1) * NBATCH + b) * BPB);
      if (t == 0) {
        u64* slot = ws + (grp + rank) * BSLOT_U64;
        const int l = besti - base;
        const unsigned xb = __float_as_uint(s_pts[3 * l + 0]);
        const unsigned yb = __float_as_uint(s_pts[3 * l + 1]);
        const unsigned zb = __float_as_uint(s_pts[3 * l + 2]);
        const u64 vb = (u64)__double_as_longlong(bestv);
        const u64 ti = (mm << 16) | (u64)(unsigned)besti;
        st_agent(&slot[0], (vb << 32) | ti);
        st_agent(&slot[1], (vb & 0xFFFFFFFF00000000ull) | ti);
        st_agent(&slot[2], ((u64)xb << 32) | (mm << 16) | (u64)(yb >> 16));
        st_agent(&slot[3], ((u64)(yb & 0xFFFFu) << 48) | ((u64)zb << 16) | mm);
      }
      if (t < BPB) {
        const u64* rs = ws + (grp + t) * BSLOT_U64;
        u64 A, B, C, D;
        for (;;) {
          A = ld_agent(rs + 0);
          B = ld_agent(rs + 1);
          C = ld_agent(rs + 2);
          D = ld_agent(rs + 3);
          const bool ok = (((A >> 16) & 0xFFFFull) == mm) &
                          (((B >> 16) & 0xFFFFull) == mm) &
                          (((C >> 16) & 0xFFFFull) == mm) &
                          ((D & 0xFFFFull) == mm);
          if (ok) break;
        }
        double v = __longlong_as_double(
            (long long)((B & 0xFFFFFFFF00000000ull) | (A >> 32)));
        int   i = (int)(A & 0xFFFFull);
        float fx = __uint_as_float((unsigned)(C >> 32));
        float fy = __uint_as_float((unsigned)(((C & 0xFFFFull) << 16) | (D >> 48)));
        float fz = __uint_as_float((unsigned)((D >> 16) & 0xFFFFFFFFull));
        int r = t;
#pragma unroll
        for (int off = BPB / 2; off >= 1; off >>= 1) {
          const double ov = __shfl_xor(v, off, 64);
          const int    oi = __shfl_xor(i, off, 64);
          const int    orr = __shfl_xor(r, off, 64);
          if (ov > v || (ov == v && oi < i)) { v = ov; i = oi; r = orr; }
        }
        fx = __shfl(fx, r, 64);
        fy = __shfl(fy, r, 64);
        fz = __shfl(fz, r, 64);
        if (t == 0) {
          s_c[0] = fx; s_c[1] = fy; s_c[2] = fz;
          if (rank == 0) o[m] = i;
        }
      }
    }
    __syncthreads();
  }
}

extern "C" void kernel_launch(void* const* d_in, const int* in_sizes, int n_in,
                              void* d_out, int out_size, void* d_ws, size_t ws_size,
                              hipStream_t stream) {
  const float* pts = (const float*)d_in[0];
  int* out = (int*)d_out;
  const int B = in_sizes[0] / (N_PTS * 3);   // 16
  if (ws_size >= WS_NEED) {
    // New path: 2 x 16 x 128 slots x 32 B = 128 KB workspace.
    hipLaunchKernelGGL(fps_wavepub, dim3(BPB, B), dim3(NT), 0, stream,
                       pts, out, (u64*)d_ws);
  } else {
    // Proven baseline (64 KB workspace).
    hipLaunchKernelGGL(fps_multi, dim3(BPB, B), dim3(NT), 0, stream,
                       pts, out, (u64*)d_ws);
  }
}

// Round 6
// 7167.622 us; speedup vs baseline: 1.7936x; 1.7936x over previous
//
#include <hip/hip_runtime.h>

// Farthest Point Sampling: points (B, N, 3) fp32 -> indices (B, M) int32.
// B=16, N=65536, M=2048.  Reference semantics (locked, absmax=0):
// float64 pipeline: dx=(double)x-(double)cx; d=((dx*dx+dy*dy)+dz*dz) with
// separate rounding (no FMA); min via fmin; argmax first-index tie-break.
//
// Transport (byte-identical to the proven 5839us baseline): 4 self-tagged
// 8-B relaxed agent-scope words per (parity, batch, rank) 128-B slot:
//   A = value_lo32<<32 | m<<16 | idx          (idx<65536: 16b)
//   B = value_hi32<<32 | m<<16 | idx
//   C = x_bits<<32     | m<<16 | y_hi16
//   D = y_lo16<<48     | z_bits<<16 | m
// Aligned 8-B stores are single-copy atomic; every word carries m => torn
// epoch mixes are re-polled.  Parity reuse safety: slot rewritten at m+2
// only after its writer saw all tags m+1, which post only after every
// block finished reading m.  0xAA poison tag != any m => no init kernel.
//
// Round 11: WAVE-ROLE SPLIT (R3/R4/R5 verdict: the agent transport is the
// best measured — ~1 poll round/iter; all fancy transports lost).  The
// hidden cost in the baseline was vmcnt ack-drain: lane t==0 both STORES
// (publish) and LOADS (poll); vmcnt is per-wave FIFO, so wave0's first
// poll waitcnt drained the 4 agent-store acks (~2000 cy) every iteration,
// and o[m]'s ack drained at the next __syncthreads' mandatory vmcnt(0).
// Fix, keeping the proven protocol bit-for-bit:
//  * wave1 = reducer+publisher: 8-way reduce of s_bv/s_bi, lane 64 does
//    the 4 slot stores.  Acks drain at ITS next barrier, ~overlapped.
//  * wave0 = pure poller: NO global stores ever -> clean vmcnt queue; goes
//    straight from barrier to poll (local reduce off the critical path).
//  * barrier2 replaced by a tagged LDS mailbox (R5-proven mechanism,
//    intra-block): waves 1-7 spin on 3 tagged words; wave0 keeps the
//    centroid in-register.
//  * o[m] -> LDS s_out, flushed once after the loop: no per-iter output
//    store acks anywhere.
// Safety induction (re-verified): wave w's s_bv[w] overwrite at m+1 is
// ordered after wave1's s_bv read at m via: w passed mailbox(m) <= wave0
// wrote mailbox(m) <= wave0 saw slot(self,m) <= wave1 published(m) <=
// wave1 read s_bv(m).  Mailbox parity reuse follows the same chain.

#define N_PTS   65536
#define M_SAMP  2048
#define NT      512
#define BPB     16                  // blocks per batch
#define PTS_BLK (N_PTS / BPB)       // 4096
#define PPT     (PTS_BLK / NT)      // 8 points per thread
#define NWAVES  (NT / 64)           // 8
#define NBATCH  16
#define SLOT_U64 16                 // 128 B per slot (as baseline; ws 64 KB)

typedef unsigned long long u64;

__device__ __forceinline__ u64 ld_agent(const u64* a) {
  return __hip_atomic_load(a, __ATOMIC_RELAXED, __HIP_MEMORY_SCOPE_AGENT);
}
__device__ __forceinline__ void st_agent(u64* a, u64 v) {
  __hip_atomic_store(a, v, __ATOMIC_RELAXED, __HIP_MEMORY_SCOPE_AGENT);
}
__device__ __forceinline__ u64 ld_lds(const u64* a) {
  return __hip_atomic_load(a, __ATOMIC_RELAXED, __HIP_MEMORY_SCOPE_WORKGROUP);
}
__device__ __forceinline__ void st_lds(u64* a, u64 v) {
  __hip_atomic_store(a, v, __ATOMIC_RELAXED, __HIP_MEMORY_SCOPE_WORKGROUP);
}

__global__ __launch_bounds__(NT, 2)
void fps_split(const float* __restrict__ pts, int* __restrict__ out,
               u64* __restrict__ ws) {
  const int rank = blockIdx.x;                 // 0..BPB-1 within batch
  const int b    = blockIdx.y;                 // batch
  const float* __restrict__ p = pts + (size_t)b * (size_t)(N_PTS * 3);
  int* __restrict__ o = out + (size_t)b * M_SAMP;
  const int t = threadIdx.x;
  const int w = t >> 6, lane = t & 63;
  const int base = rank * PTS_BLK;

  __shared__ float  s_pts[PTS_BLK * 3];        // 48 KB slice
  __shared__ double s_bv[NWAVES];
  __shared__ int    s_bi[NWAVES];
  __shared__ u64    sMB[2][3];                 // tagged centroid mailbox
  __shared__ int    s_out[M_SAMP];             // output indices (rank0 only)

  for (int i = t; i < PTS_BLK * 3; i += NT)
    s_pts[i] = p[base * 3 + i];
  if (t == 0) s_out[0] = 0;                    // seed index
  if (t < 6) sMB[t / 3][t % 3] = 0xAAAAAAAAAAAAAAAAull;   // poison mailbox
  __syncthreads();

  // Own points pre-converted to f64 in registers; (double)x is exact.
  double pd[PPT][3];
  double md[PPT];
#pragma unroll
  for (int j = 0; j < PPT; ++j) {
    const int l = t + j * NT;
    pd[j][0] = (double)s_pts[3 * l + 0];
    pd[j][1] = (double)s_pts[3 * l + 1];
    pd[j][2] = (double)s_pts[3 * l + 2];
    md[j] = 1e10;
  }

  // Seed centroid = point 0 of this batch (read-only, cached; R5-proven).
  double cx = (double)p[0], cy = (double)p[1], cz = (double)p[2];

  for (int m = 1; m < M_SAMP; ++m) {
    double bestv = -1.0;    // distances >= 0 always beat this
    int    besti = 0;

    // Indices base + t + j*NT ascend with j => strict '>' keeps the first
    // (lowest-index) maximum within a thread.
#pragma unroll
    for (int j = 0; j < PPT; ++j) {
      const double dx = __dsub_rn(pd[j][0], cx);
      const double dy = __dsub_rn(pd[j][1], cy);
      const double dz = __dsub_rn(pd[j][2], cz);
      const double d  = __dadd_rn(__dadd_rn(__dmul_rn(dx, dx),
                                            __dmul_rn(dy, dy)),
                                  __dmul_rn(dz, dz));
      const double nmd = fmin(md[j], d);
      md[j] = nmd;
      if (nmd > bestv) { bestv = nmd; besti = base + t + j * NT; }
    }

    // 64-lane butterfly argmax, min-index tie-break.
#pragma unroll
    for (int off = 32; off >= 1; off >>= 1) {
      const double ov = __shfl_xor(bestv, off, 64);
      const int    oi = __shfl_xor(besti, off, 64);
      if (ov > bestv || (ov == bestv && oi < besti)) { bestv = ov; besti = oi; }
    }
    if (lane == 0) { s_bv[w] = bestv; s_bi[w] = besti; }
    __syncthreads();                           // barrier1 (only one in loop)

    const u64 mm  = (u64)(unsigned)m;
    const int par = m & 1;
    const u64 grp = (u64)((par * NBATCH + b) * BPB);

    if (w == 1) {
      // Wave 1: block reduce + publish.  Store acks drain at ITS next
      // barrier (~2900 cy after issue) — fully overlapped with the poll.
      double rv = -1.0;
      int    ri = 0x7FFFFFFF;
      if (lane < NWAVES) { rv = s_bv[lane]; ri = s_bi[lane]; }
#pragma unroll
      for (int off = NWAVES / 2; off >= 1; off >>= 1) {
        const double ov = __shfl_xor(rv, off, 64);
        const int    oi = __shfl_xor(ri, off, 64);
        if (ov > rv || (ov == rv && oi < ri)) { rv = ov; ri = oi; }
      }
      if (lane == 0) {
        u64* slot = ws + (grp + rank) * SLOT_U64;
        const int l = ri - base;               // block winner is in our slice
        const unsigned xb = __float_as_uint(s_pts[3 * l + 0]);
        const unsigned yb = __float_as_uint(s_pts[3 * l + 1]);
        const unsigned zb = __float_as_uint(s_pts[3 * l + 2]);
        const u64 vb = (u64)__double_as_longlong(rv);
        const u64 ti = (mm << 16) | (u64)(unsigned)ri;
        st_agent(&slot[0], (vb << 32) | ti);                          // A
        st_agent(&slot[1], (vb & 0xFFFFFFFF00000000ull) | ti);        // B
        st_agent(&slot[2], ((u64)xb << 32) | (mm << 16) | (u64)(yb >> 16));     // C
        st_agent(&slot[3], ((u64)(yb & 0xFFFFu) << 48) | ((u64)zb << 16) | mm); // D
      }
    }

    if (w == 0) {
      // Wave 0: pure poller — zero global stores ever, clean vmcnt queue.
      unsigned cxb = 0, cyb = 0, czb = 0;
      int ii = 0;
      if (lane < BPB) {
        const u64* rs = ws + (grp + lane) * SLOT_U64;
        u64 A, B, C, D;
        for (;;) {
          A = ld_agent(rs + 0);
          B = ld_agent(rs + 1);
          C = ld_agent(rs + 2);
          D = ld_agent(rs + 3);
          const bool ok = (((A >> 16) & 0xFFFFull) == mm) &
                          (((B >> 16) & 0xFFFFull) == mm) &
                          (((C >> 16) & 0xFFFFull) == mm) &
                          ((D & 0xFFFFull) == mm);
          if (ok) break;
        }
        double v = __longlong_as_double(
            (long long)((B & 0xFFFFFFFF00000000ull) | (A >> 32)));
        ii = (int)(A & 0xFFFFull);
        float fx = __uint_as_float((unsigned)(C >> 32));
        float fy = __uint_as_float((unsigned)(((C & 0xFFFFull) << 16) | (D >> 48)));
        float fz = __uint_as_float((unsigned)((D >> 16) & 0xFFFFFFFFull));
        int r = lane;                           // contributing rank
#pragma unroll
        for (int off = BPB / 2; off >= 1; off >>= 1) {
          const double ov = __shfl_xor(v, off, 64);
          const int    oi = __shfl_xor(ii, off, 64);
          const int    orr = __shfl_xor(r, off, 64);
          if (ov > v || (ov == v && oi < ii)) { v = ov; ii = oi; r = orr; }
        }
        // Lanes 0..15 agree on winner rank r; pull its coords by shuffle.
        fx = __shfl(fx, r, 64);
        fy = __shfl(fy, r, 64);
        fz = __shfl(fz, r, 64);
        cxb = __float_as_uint(fx);
        cyb = __float_as_uint(fy);
        czb = __float_as_uint(fz);
      }
      // Broadcast winner from lane 0 to the whole wave (lanes 16-63 too).
      cxb = (unsigned)__shfl((int)cxb, 0, 64);
      cyb = (unsigned)__shfl((int)cyb, 0, 64);
      czb = (unsigned)__shfl((int)czb, 0, 64);
      ii  = __shfl(ii, 0, 64);
      if (lane == 0) {
        if (rank == 0) s_out[m] = ii;           // LDS only — no global store
        st_lds(&sMB[par][0], ((u64)cxb << 32) | mm);
        st_lds(&sMB[par][1], ((u64)cyb << 32) | mm);
        st_lds(&sMB[par][2], ((u64)czb << 32) | mm);
      }
      cx = (double)__uint_as_float(cxb);
      cy = (double)__uint_as_float(cyb);
      cz = (double)__uint_as_float(czb);
    } else {
      // Waves 1-7: spin on the tagged LDS mailbox (intra-CU; R5-proven).
      u64 l0, l1, l2;
      for (;;) {
        l0 = ld_lds(&sMB[par][0]);
        l1 = ld_lds(&sMB[par][1]);
        l2 = ld_lds(&sMB[par][2]);
        const bool ok = ((l0 & 0xFFFFull) == mm) &
                        ((l1 & 0xFFFFull) == mm) &
                        ((l2 & 0xFFFFull) == mm);
        if (ok) break;
      }
      cx = (double)__uint_as_float((unsigned)(l0 >> 32));
      cy = (double)__uint_as_float((unsigned)(l1 >> 32));
      cz = (double)__uint_as_float((unsigned)(l2 >> 32));
    }
  }

  // Single output flush (rank 0 only): the only global output stores.
  __syncthreads();
  if (rank == 0)
    for (int i = t; i < M_SAMP; i += NT) o[i] = s_out[i];
}

extern "C" void kernel_launch(void* const* d_in, const int* in_sizes, int n_in,
                              void* d_out, int out_size, void* d_ws, size_t ws_size,
                              hipStream_t stream) {
  const float* pts = (const float*)d_in[0];
  int* out = (int*)d_out;
  const int B = in_sizes[0] / (N_PTS * 3);   // 16
  // ws usage: 2 * 16 * 16 slots * 128 B = 64 KB (identical to baseline).
  hipLaunchKernelGGL(fps_split, dim3(BPB, B), dim3(NT), 0, stream,
                     pts, out, (u64*)d_ws);
}

// Round 7
// 5815.422 us; speedup vs baseline: 2.2107x; 1.2325x over previous
//
#include <hip/hip_runtime.h>

// Farthest Point Sampling: points (B, N, 3) fp32 -> indices (B, M) int32.
// B=16, N=65536, M=2048.  Reference semantics (locked, absmax=0):
// float64 pipeline: dx=(double)x-(double)cx; d=((dx*dx+dy*dy)+dz*dz) with
// separate rounding (no FMA); min via fmin; argmax first-index tie-break.
//
// Structure = the proven 5839us baseline (R3/R4/R5/R6 all lost to it):
// block-level exchange, 4 self-tagged 8-B relaxed agent-scope words per
// (parity, batch, rank) 128-B slot:
//   A = value_lo32<<32 | m<<16 | idx          (idx<65536, m<2048: 16b each)
//   B = value_hi32<<32 | m<<16 | idx
//   C = x_bits<<32     | m<<16 | y_hi16
//   D = y_lo16<<48     | z_bits<<16 | m
// Aligned 8-B stores are single-copy atomic; every word carries m => torn
// epoch mixes are re-polled.  Parity (m&1) reuse safety: slot rewritten at
// m+2 only after its writer saw all tags m+1, which post only after every
// block finished reading m.  0xAA poison tag != any m => no init kernel.
//
// Round 12 (after R6 regression, reverted role-split):
// R6 lessons: spin-waves co-resident with the critical wave steal issue
// slots (VALUBusy 19->35%, +1300us) — barrier-sleeping waves are free;
// and polling before publish wastes a round.  Baseline ordering restored.
// Two surgical edits only:
//  * 2-DEEP PIPELINED POLL: two register sets of the 4 slot words, issued
//    back-to-back; each check waits only its own set (vmcnt(4)) while the
//    other stays in flight, then reissues.  Halves the miss-detection
//    quantum (~500 cy/round -> ~250 cy effective).  Atomic loads cannot be
//    merged by the compiler, so both rounds really issue.  Discarded
//    in-flight loads drain harmlessly at barrier2's vmcnt(0).
//  * o[m] -> LDS s_out, flushed once after the loop (removes the odd
//    output-store ack from rank0's wave0 queue; proven-safe local change).

#define N_PTS   65536
#define M_SAMP  2048
#define NT      512
#define BPB     16                  // blocks per batch
#define PTS_BLK (N_PTS / BPB)       // 4096
#define PPT     (PTS_BLK / NT)      // 8 points per thread
#define NWAVES  (NT / 64)           // 8
#define NBATCH  16
#define SLOT_U64 16                 // 128 B per slot

typedef unsigned long long u64;

__device__ __forceinline__ u64 ld_agent(const u64* a) {
  return __hip_atomic_load(a, __ATOMIC_RELAXED, __HIP_MEMORY_SCOPE_AGENT);
}
__device__ __forceinline__ void st_agent(u64* a, u64 v) {
  __hip_atomic_store(a, v, __ATOMIC_RELAXED, __HIP_MEMORY_SCOPE_AGENT);
}
__device__ __forceinline__ bool tagok(u64 A, u64 B, u64 C, u64 D, u64 mm) {
  return (((A >> 16) & 0xFFFFull) == mm) &
         (((B >> 16) & 0xFFFFull) == mm) &
         (((C >> 16) & 0xFFFFull) == mm) &
         ((D & 0xFFFFull) == mm);
}

__global__ __launch_bounds__(NT, 2)
void fps_multi(const float* __restrict__ pts, int* __restrict__ out,
               u64* __restrict__ ws) {
  const int rank = blockIdx.x;                 // 0..BPB-1 within batch
  const int b    = blockIdx.y;                 // batch
  const float* __restrict__ p = pts + (size_t)b * (size_t)(N_PTS * 3);
  int* __restrict__ o = out + (size_t)b * M_SAMP;
  const int t = threadIdx.x;
  const int base = rank * PTS_BLK;

  __shared__ float  s_pts[PTS_BLK * 3];        // 48 KB slice
  __shared__ double s_bv[NWAVES];
  __shared__ int    s_bi[NWAVES];
  __shared__ float  s_c[3];                    // broadcast centroid coords
  __shared__ int    s_out[M_SAMP];             // output staging (rank0 use)

  for (int i = t; i < PTS_BLK * 3; i += NT)
    s_pts[i] = p[base * 3 + i];
  if (t == 0) { s_out[0] = 0; }
  if (t == 0) { s_c[0] = p[0]; s_c[1] = p[1]; s_c[2] = p[2]; }  // seed pt 0
  __syncthreads();

  // Own points pre-converted to f64 in registers; (double)x is exact.
  double pd[PPT][3];
  double md[PPT];
#pragma unroll
  for (int j = 0; j < PPT; ++j) {
    const int l = t + j * NT;
    pd[j][0] = (double)s_pts[3 * l + 0];
    pd[j][1] = (double)s_pts[3 * l + 1];
    pd[j][2] = (double)s_pts[3 * l + 2];
    md[j] = 1e10;
  }

  for (int m = 1; m < M_SAMP; ++m) {
    const double cx = (double)s_c[0];
    const double cy = (double)s_c[1];
    const double cz = (double)s_c[2];

    double bestv = -1.0;    // distances >= 0 always beat this
    int    besti = 0;

    // Indices base + t + j*NT ascend with j => strict '>' keeps the first
    // (lowest-index) maximum within a thread.
#pragma unroll
    for (int j = 0; j < PPT; ++j) {
      const double dx = __dsub_rn(pd[j][0], cx);
      const double dy = __dsub_rn(pd[j][1], cy);
      const double dz = __dsub_rn(pd[j][2], cz);
      const double d  = __dadd_rn(__dadd_rn(__dmul_rn(dx, dx),
                                            __dmul_rn(dy, dy)),
                                  __dmul_rn(dz, dz));
      const double nmd = fmin(md[j], d);
      md[j] = nmd;
      if (nmd > bestv) { bestv = nmd; besti = base + t + j * NT; }
    }

    // 64-lane butterfly argmax, min-index tie-break.
#pragma unroll
    for (int off = 32; off >= 1; off >>= 1) {
      const double ov = __shfl_xor(bestv, off, 64);
      const int    oi = __shfl_xor(besti, off, 64);
      if (ov > bestv || (ov == bestv && oi < besti)) { bestv = ov; besti = oi; }
    }
    if ((t & 63) == 0) { s_bv[t >> 6] = bestv; s_bi[t >> 6] = besti; }
    __syncthreads();

    // Wave 0: finish block reduction, publish, poll, cross-block reduce.
    if (t < 64) {
      if (t < NWAVES) {
        bestv = s_bv[t]; besti = s_bi[t];
#pragma unroll
        for (int off = NWAVES / 2; off >= 1; off >>= 1) {
          const double ov = __shfl_xor(bestv, off, 64);
          const int    oi = __shfl_xor(besti, off, 64);
          if (ov > bestv || (ov == bestv && oi < besti)) { bestv = ov; besti = oi; }
        }
      }
      const u64 mm  = (u64)(unsigned)m;
      const u64 grp = (u64)(((m & 1) * NBATCH + b) * BPB);
      if (t == 0) {
        u64* slot = ws + (grp + rank) * SLOT_U64;
        const int l = besti - base;           // block winner is in our slice
        const unsigned xb = __float_as_uint(s_pts[3 * l + 0]);
        const unsigned yb = __float_as_uint(s_pts[3 * l + 1]);
        const unsigned zb = __float_as_uint(s_pts[3 * l + 2]);
        const u64 vb = (u64)__double_as_longlong(bestv);
        const u64 ti = (mm << 16) | (u64)(unsigned)besti;
        st_agent(&slot[0], (vb << 32) | ti);                          // A
        st_agent(&slot[1], (vb & 0xFFFFFFFF00000000ull) | ti);        // B
        st_agent(&slot[2], ((u64)xb << 32) | (mm << 16) | (u64)(yb >> 16));          // C
        st_agent(&slot[3], ((u64)(yb & 0xFFFFu) << 48) | ((u64)zb << 16) | mm);      // D
      }
      if (t < BPB) {
        const u64* rs = ws + (grp + t) * SLOT_U64;
        u64 A, B, C, D;
        // 2-deep software-pipelined poll: two rounds in flight; each check
        // waits only its own round (vmcnt(4)), halving detection quantum.
        u64 a0 = ld_agent(rs + 0), b0 = ld_agent(rs + 1),
            c0 = ld_agent(rs + 2), d0 = ld_agent(rs + 3);
        u64 a1 = ld_agent(rs + 0), b1 = ld_agent(rs + 1),
            c1 = ld_agent(rs + 2), d1 = ld_agent(rs + 3);
        for (;;) {
          if (tagok(a0, b0, c0, d0, mm)) { A = a0; B = b0; C = c0; D = d0; break; }
          a0 = ld_agent(rs + 0); b0 = ld_agent(rs + 1);
          c0 = ld_agent(rs + 2); d0 = ld_agent(rs + 3);
          if (tagok(a1, b1, c1, d1, mm)) { A = a1; B = b1; C = c1; D = d1; break; }
          a1 = ld_agent(rs + 0); b1 = ld_agent(rs + 1);
          c1 = ld_agent(rs + 2); d1 = ld_agent(rs + 3);
        }
        double v = __longlong_as_double(
            (long long)((B & 0xFFFFFFFF00000000ull) | (A >> 32)));
        int   i = (int)(A & 0xFFFFull);
        float fx = __uint_as_float((unsigned)(C >> 32));
        float fy = __uint_as_float((unsigned)(((C & 0xFFFFull) << 16) | (D >> 48)));
        float fz = __uint_as_float((unsigned)((D >> 16) & 0xFFFFFFFFull));
        int r = t;                              // contributing rank
#pragma unroll
        for (int off = BPB / 2; off >= 1; off >>= 1) {
          const double ov = __shfl_xor(v, off, 64);
          const int    oi = __shfl_xor(i, off, 64);
          const int    orr = __shfl_xor(r, off, 64);
          if (ov > v || (ov == v && oi < i)) { v = ov; i = oi; r = orr; }
        }
        // Lanes 0..15 agree on winner rank r; pull its coords by shuffle.
        fx = __shfl(fx, r, 64);
        fy = __shfl(fy, r, 64);
        fz = __shfl(fz, r, 64);
        if (t == 0) {
          s_c[0] = fx; s_c[1] = fy; s_c[2] = fz;
          if (rank == 0) s_out[m] = i;          // LDS only; flushed at end
        }
      }
    }
    __syncthreads();
  }

  // Single output flush (rank 0 of each batch).
  if (rank == 0)
    for (int i = t; i < M_SAMP; i += NT) o[i] = s_out[i];
}

extern "C" void kernel_launch(void* const* d_in, const int* in_sizes, int n_in,
                              void* d_out, int out_size, void* d_ws, size_t ws_size,
                              hipStream_t stream) {
  const float* pts = (const float*)d_in[0];
  int* out = (int*)d_out;
  const int B = in_sizes[0] / (N_PTS * 3);   // 16
  // ws usage: 2 * 16 * 16 slots * 128 B = 64 KB (identical to baseline).
  hipLaunchKernelGGL(fps_multi, dim3(BPB, B), dim3(NT), 0, stream,
                     pts, out, (u64*)d_ws);
}

// Round 8
// 5625.172 us; speedup vs baseline: 2.2854x; 1.0338x over previous
//
#include <hip/hip_runtime.h>

// Farthest Point Sampling: points (B, N, 3) fp32 -> indices (B, M) int32.
// B=16, N=65536, M=2048.  Reference semantics (locked, absmax=0):
// float64 pipeline: dx=(double)x-(double)cx; d=((dx*dx+dy*dy)+dz*dz) with
// separate rounding (no FMA); min via fmin; argmax first-index tie-break.
//
// Transport: 4 self-tagged 8-B words per (parity, batch, rank) 64-B slot:
//   A = value_lo32<<32 | m<<16 | idx          (idx<65536, m<2048: 16b each)
//   B = value_hi32<<32 | m<<16 | idx
//   C = x_bits<<32     | m<<16 | y_hi16
//   D = y_lo16<<48     | z_bits<<16 | m
// Aligned 8-B stores are single-copy atomic; every word carries m => torn
// epoch mixes are re-polled.  Parity (m&1) reuse safety: slot rewritten at
// m+2 only after its writer saw all tags m+1, which post only after every
// block finished reading m.  0xAA poison tag != any m => no init kernel.
//
// Round 13: L2-LOCAL POLL VIA L1-INVALIDATE (last untried mechanism).
// Ledger: R3 proved swizzle co-locates a batch on one XCD and st_wg is
// visible to local-L2 readers (FETCH 277->6 MB); R3/R4 proved CAS polling
// loses (RMW serialization); R6 proved spin-waves poison the CU; R7 proved
// poll pipelining is null => the cost is the MALL RT itself (~1600+ cy),
// not detection quantum.  Remaining lever: poll the LOCAL L2 (~250 cy RT)
// with PLAIN loads, breaking L1 staleness with `buffer_inv sc0` (L1-only
// invalidate; the acquire-fence instruction on gfx94x+).  No RMW => no L2
// serialization; nothing else global is read in the loop => inv is free.
// Hang-proof (R4 pattern): bounded spins, PERMANENT demotion, agent channel
// always written.  Staleness-detecting probe: m==1 warms L1 with the fast
// line; m==2 probes THROUGH inv expecting tag 2 — a no-op inv sees stale 1
// and demotes cleanly (one-time ~10 us), never trusting first-touch misses.
// Worst case = proven baseline + ~10 us.  Correctness never depends on
// placement (G16): any miss -> agent path, bit-identical payloads.

#define N_PTS   65536
#define M_SAMP  2048
#define NT      512
#define BPB     16                  // blocks per batch
#define PTS_BLK (N_PTS / BPB)       // 4096
#define PPT     (PTS_BLK / NT)      // 8 points per thread
#define NWAVES  (NT / 64)           // 8
#define NBATCH  16
#define SLOT_U64 8                  // 64-B slots (R3/R4-proven layout)
#define FAST_OFF (2 * NBATCH * BPB * SLOT_U64)   // agent 32 KB + fast 32 KB
#define PROBE_SPINS 64
#define FAST_SPINS  64

typedef unsigned long long u64;

__device__ __forceinline__ u64 ld_agent(const u64* a) {
  return __hip_atomic_load(a, __ATOMIC_RELAXED, __HIP_MEMORY_SCOPE_AGENT);
}
__device__ __forceinline__ void st_agent(u64* a, u64 v) {
  __hip_atomic_store(a, v, __ATOMIC_RELAXED, __HIP_MEMORY_SCOPE_AGENT);
}
// Workgroup-scope ops compile to plain global_load/store: stores are
// write-through L1 -> local L2 (R3-proven visible); loads may hit L1 —
// staleness is broken explicitly with buffer_inv below.
__device__ __forceinline__ u64 ld_wg(const u64* a) {
  return __hip_atomic_load(a, __ATOMIC_RELAXED, __HIP_MEMORY_SCOPE_WORKGROUP);
}
__device__ __forceinline__ void st_wg(u64* a, u64 v) {
  __hip_atomic_store(a, v, __ATOMIC_RELAXED, __HIP_MEMORY_SCOPE_WORKGROUP);
}
// L1-only invalidate (vector cache). CU-local; ignores EXEC; nothing else
// global is live in the loop, so invalidation costs ~nothing.
__device__ __forceinline__ void l1_inv() {
  asm volatile("buffer_inv sc0" ::: "memory");
}
__device__ __forceinline__ bool tagok(u64 A, u64 B, u64 C, u64 D, u64 mm) {
  return (((A >> 16) & 0xFFFFull) == mm) &
         (((B >> 16) & 0xFFFFull) == mm) &
         (((C >> 16) & 0xFFFFull) == mm) &
         ((D & 0xFFFFull) == mm);
}

__global__ __launch_bounds__(NT, 2)
void fps_multi(const float* __restrict__ pts, int* __restrict__ out,
               u64* __restrict__ ws) {
  // Placement: 1D launch uses the R3-proven swizzle (batch b owns lids
  // {(b&7) + 8*(2r + (b>>3))} — all congruent mod 8 => one XCD under
  // round-robin dispatch).  2D launch = baseline mapping (fallback).
  int b, rank;
  if (gridDim.y == 1) {
    const int lid  = blockIdx.x;
    const int slot = lid >> 3;
    b    = (lid & 7) + ((slot & 1) << 3);
    rank = slot >> 1;
  } else {
    rank = blockIdx.x; b = blockIdx.y;
  }
  const float* __restrict__ p = pts + (size_t)b * (size_t)(N_PTS * 3);
  int* __restrict__ o = out + (size_t)b * M_SAMP;
  const int t = threadIdx.x;
  const int base = rank * PTS_BLK;

  __shared__ float  s_pts[PTS_BLK * 3];        // 48 KB slice
  __shared__ double s_bv[NWAVES];
  __shared__ int    s_bi[NWAVES];
  __shared__ float  s_c[3];                    // broadcast centroid coords
  __shared__ int    s_out[M_SAMP];             // output staging (rank0 use)

  for (int i = t; i < PTS_BLK * 3; i += NT)
    s_pts[i] = p[base * 3 + i];
  if (t == 0) { s_out[0] = 0; }
  if (t == 0) { s_c[0] = p[0]; s_c[1] = p[1]; s_c[2] = p[2]; }  // seed pt 0
  __syncthreads();

  // Own points pre-converted to f64 in registers; (double)x is exact.
  double pd[PPT][3];
  double md[PPT];
#pragma unroll
  for (int j = 0; j < PPT; ++j) {
    const int l = t + j * NT;
    pd[j][0] = (double)s_pts[3 * l + 0];
    pd[j][1] = (double)s_pts[3 * l + 1];
    pd[j][2] = (double)s_pts[3 * l + 2];
    md[j] = 1e10;
  }

  bool fast = false;     // per reader lane (t<16): L2-local poll verified

  for (int m = 1; m < M_SAMP; ++m) {
    const double cx = (double)s_c[0];
    const double cy = (double)s_c[1];
    const double cz = (double)s_c[2];

    double bestv = -1.0;    // distances >= 0 always beat this
    int    besti = 0;

    // Indices base + t + j*NT ascend with j => strict '>' keeps the first
    // (lowest-index) maximum within a thread.
#pragma unroll
    for (int j = 0; j < PPT; ++j) {
      const double dx = __dsub_rn(pd[j][0], cx);
      const double dy = __dsub_rn(pd[j][1], cy);
      const double dz = __dsub_rn(pd[j][2], cz);
      const double d  = __dadd_rn(__dadd_rn(__dmul_rn(dx, dx),
                                            __dmul_rn(dy, dy)),
                                  __dmul_rn(dz, dz));
      const double nmd = fmin(md[j], d);
      md[j] = nmd;
      if (nmd > bestv) { bestv = nmd; besti = base + t + j * NT; }
    }

    // 64-lane butterfly argmax, min-index tie-break.
#pragma unroll
    for (int off = 32; off >= 1; off >>= 1) {
      const double ov = __shfl_xor(bestv, off, 64);
      const int    oi = __shfl_xor(besti, off, 64);
      if (ov > bestv || (ov == bestv && oi < besti)) { bestv = ov; besti = oi; }
    }
    if ((t & 63) == 0) { s_bv[t >> 6] = bestv; s_bi[t >> 6] = besti; }
    __syncthreads();

    // Wave 0: finish block reduction, publish, poll, cross-block reduce.
    if (t < 64) {
      if (t < NWAVES) {
        bestv = s_bv[t]; besti = s_bi[t];
#pragma unroll
        for (int off = NWAVES / 2; off >= 1; off >>= 1) {
          const double ov = __shfl_xor(bestv, off, 64);
          const int    oi = __shfl_xor(besti, off, 64);
          if (ov > bestv || (ov == bestv && oi < besti)) { bestv = ov; besti = oi; }
        }
      }
      const u64 mm  = (u64)(unsigned)m;
      const u64 grp = (u64)(((m & 1) * NBATCH + b) * BPB);
      if (t == 0) {
        const int l = besti - base;           // block winner is in our slice
        const unsigned xb = __float_as_uint(s_pts[3 * l + 0]);
        const unsigned yb = __float_as_uint(s_pts[3 * l + 1]);
        const unsigned zb = __float_as_uint(s_pts[3 * l + 2]);
        const u64 vb = (u64)__double_as_longlong(bestv);
        const u64 ti = (mm << 16) | (u64)(unsigned)besti;
        const u64 Aw = (vb << 32) | ti;
        const u64 Bw = (vb & 0xFFFFFFFF00000000ull) | ti;
        const u64 Cw = ((u64)xb << 32) | (mm << 16) | (u64)(yb >> 16);
        const u64 Dw = ((u64)(yb & 0xFFFFu) << 48) | ((u64)zb << 16) | mm;
        // Fast (local-L2) copy first, then the always-available agent copy.
        u64* fsw = ws + FAST_OFF + (grp + rank) * SLOT_U64;
        st_wg(fsw + 0, Aw);
        st_wg(fsw + 1, Bw);
        st_wg(fsw + 2, Cw);
        st_wg(fsw + 3, Dw);
        u64* s = ws + (grp + rank) * SLOT_U64;
        st_agent(&s[0], Aw);
        st_agent(&s[1], Bw);
        st_agent(&s[2], Cw);
        st_agent(&s[3], Dw);
      }
      if (t < BPB) {
        u64 A, B, C, D;
        bool got = false;
        const u64* fs = ws + FAST_OFF + (grp + t) * SLOT_U64;
        if (fast) {
          // L2-local poll: invalidate L1, plain-load the 4 tagged words.
          for (int sp = 0; sp < FAST_SPINS; ++sp) {
            l1_inv();
            A = ld_wg(fs + 0); B = ld_wg(fs + 1);
            C = ld_wg(fs + 2); D = ld_wg(fs + 3);
            if (tagok(A, B, C, D, mm)) { got = true; break; }
            __builtin_amdgcn_s_sleep(1);
          }
          if (!got) fast = false;   // permanent demotion; agent always written
        }
        if (!got) {
          const u64* rs = ws + (grp + t) * SLOT_U64;
          for (;;) {
            A = ld_agent(rs + 0);
            B = ld_agent(rs + 1);
            C = ld_agent(rs + 2);
            D = ld_agent(rs + 3);
            if (tagok(A, B, C, D, mm)) break;
          }
          if (m == 1) {
            // Warm L1 with the fast line (stale-detection setup for m==2).
            u64 w0 = ld_wg(fs + 0), w1 = ld_wg(fs + 1);
            u64 w2 = ld_wg(fs + 2), w3 = ld_wg(fs + 3);
            asm volatile("" :: "v"(w0), "v"(w1), "v"(w2), "v"(w3));
          } else if (m == 2) {
            // Probe THROUGH the invalidate: only a working inv can reveal
            // tag 2 under the m==1-warmed line.  No-op inv => stale 1 =>
            // stay demoted forever (one bounded spin, ~10 us, once).
            for (int sp = 0; sp < PROBE_SPINS && !fast; ++sp) {
              l1_inv();
              const u64 a2 = ld_wg(fs + 0), b2 = ld_wg(fs + 1);
              const u64 c2 = ld_wg(fs + 2), d2 = ld_wg(fs + 3);
              fast = tagok(a2, b2, c2, d2, mm);
              if (!fast) __builtin_amdgcn_s_sleep(1);
            }
          }
        }
        double v = __longlong_as_double(
            (long long)((B & 0xFFFFFFFF00000000ull) | (A >> 32)));
        int   i = (int)(A & 0xFFFFull);
        float fx = __uint_as_float((unsigned)(C >> 32));
        float fy = __uint_as_float((unsigned)(((C & 0xFFFFull) << 16) | (D >> 48)));
        float fz = __uint_as_float((unsigned)((D >> 16) & 0xFFFFFFFFull));
        int r = t;                              // contributing rank
#pragma unroll
        for (int off = BPB / 2; off >= 1; off >>= 1) {
          const double ov = __shfl_xor(v, off, 64);
          const int    oi = __shfl_xor(i, off, 64);
          const int    orr = __shfl_xor(r, off, 64);
          if (ov > v || (ov == v && oi < i)) { v = ov; i = oi; r = orr; }
        }
        // Lanes 0..15 agree on winner rank r; pull its coords by shuffle.
        fx = __shfl(fx, r, 64);
        fy = __shfl(fy, r, 64);
        fz = __shfl(fz, r, 64);
        if (t == 0) {
          s_c[0] = fx; s_c[1] = fy; s_c[2] = fz;
          if (rank == 0) s_out[m] = i;          // LDS only; flushed at end
        }
      }
    }
    __syncthreads();
  }

  // Single output flush (rank 0 of each batch).
  if (rank == 0)
    for (int i = t; i < M_SAMP; i += NT) o[i] = s_out[i];
}

extern "C" void kernel_launch(void* const* d_in, const int* in_sizes, int n_in,
                              void* d_out, int out_size, void* d_ws, size_t ws_size,
                              hipStream_t stream) {
  const float* pts = (const float*)d_in[0];
  int* out = (int*)d_out;
  const int B = in_sizes[0] / (N_PTS * 3);   // 16
  // ws usage: agent 32 KB + fast 32 KB = 64 KB (R3/R4-proven layout).
  if (B == NBATCH) {
    // 1D swizzled grid: co-locates each batch's 16 blocks on one XCD.
    hipLaunchKernelGGL(fps_multi, dim3(BPB * NBATCH), dim3(NT), 0, stream,
                       pts, out, (u64*)d_ws);
  } else {
    hipLaunchKernelGGL(fps_multi, dim3(BPB, B), dim3(NT), 0, stream,
                       pts, out, (u64*)d_ws);
  }
}